// Round 7
// baseline (99.785 us; speedup 1.0000x reference)
//
#include <hip/hip_runtime.h>
#include <math.h>
#include <stdint.h>

#define K_NN 16
#define NPTS 8192
#define HALF (NPTS / 2)     // 4096 points staged per pass (32 KB LDS)
#define STEPS (HALF / 256)  // 16 steps/pass, 256 candidates/step (4/lane)
#define WPB 16              // waves (= queries) per block; block = 1024 threads

// ---------------------------------------------------------------------------
// k1: wave-cooperative KNN, one wave per query, candidate set in LDS in two
// 32 KB passes (2 blocks/CU -> 32 waves/CU = 100% occupancy).
// Top-16 = lane-distributed sorted packed keys (dist_bits & ~0x1FFF) | idx in
// lanes 0-15 (each 16-lane DPP row holds an identical copy). Common path per
// candidate is 5 VALU: sub,sub,mul,fma,cmp -- the compare is raw nonneg-float
// bits (uint order == float order) vs wave-uniform thr = kth | 0x1FFF, using
// <= so truncated-distance ties can't be missed (false positives self-reject
// in the exact packed-key insert). Packing happens only per event, in scalar
// ops on the readlane'd bits. Insert shift = DPP row_shr:1. After each insert
// the ballot is refreshed (m &= m-1 first guarantees termination).
// k3 recomputes exact distances of the selected indices.
// ---------------------------------------------------------------------------
__global__ __launch_bounds__(1024) void k1_knn(const float* __restrict__ ch1,
                                               const float* __restrict__ ch2,
                                               const float* __restrict__ M1,
                                               const float* __restrict__ M2,
                                               int* __restrict__ midx,
                                               float* __restrict__ out) {
    __shared__ float2 sh[HALF];        // 32 KB: half the transformed ch2

    const int tid  = threadIdx.x;
    const int lane = tid & 63;
    const int w    = tid >> 6;
    const int qg   = blockIdx.x * WPB + w;

    if (blockIdx.x == 0 && tid == 0) out[0] = 0.0f;   // k3 atomics start from 0

    const float q0 = ch1[2 * qg + 0];
    const float q1 = ch1[2 * qg + 1];

    const float a0 = M1[0], a1 = M1[1], a2 = M1[2], a3 = M1[3];
    const float b0 = M2[0], b1 = M2[1], b2 = M2[2], b3 = M2[3];

    const float4* __restrict__ g4 = (const float4*)ch2;

    unsigned key = 0xFFFFFFFFu;        // lanes 0-15: sorted top-16 packed keys
    unsigned kth = 0xFFFFFFFFu;        // wave-uniform copy of lane 15's key
    unsigned thr = 0xFFFFFFFFu;        // kth | 0x1FFF (ballot threshold)

#define INSERT_EVENT(NDV, CIDX)                                                \
    {                                                                          \
        int l = __ffsll(m) - 1;                                                \
        unsigned snd = (unsigned)__builtin_amdgcn_readlane(                    \
            __float_as_int(NDV), l);                                           \
        unsigned snk = (snd & 0xFFFFE000u) | (unsigned)(sbase + (CIDX));       \
        if (snk < kth) {                                                       \
            unsigned up = (unsigned)__builtin_amdgcn_update_dpp(               \
                0, (int)key, 0x111, 0xF, 0xF, false); /* row_shr:1 */          \
            bool c1 = snk < key;                                               \
            unsigned nv = (snk < up) ? up : snk;                               \
            key = c1 ? nv : key;                                               \
            kth = (unsigned)__builtin_amdgcn_readlane((int)key, 15);           \
            thr = kth | 0x1FFFu;                                               \
        }                                                                      \
        m &= m - 1;                                                            \
        m &= __ballot(__float_as_uint(NDV) <= thr);                            \
    }

    for (int pass = 0; pass < 2; ++pass) {
        __syncthreads();               // protect sh against previous pass scan
        // stage 4096 points (poly fused): 2048 float4 / 1024 threads
#pragma unroll
        for (int e = 0; e < (HALF / 2) / 1024; ++e) {
            float4 v = g4[pass * (HALF / 2) + e * 1024 + tid];
            float px0 = a0 + a1 * v.y + v.x * (a2 + a3 * v.y);
            float py0 = b0 + b1 * v.y + v.x * (b2 + b3 * v.y);
            float px1 = a0 + a1 * v.w + v.z * (a2 + a3 * v.w);
            float py1 = b0 + b1 * v.w + v.z * (b2 + b3 * v.w);
            ((float4*)sh)[e * 1024 + tid] = make_float4(px0, py0, px1, py1);
        }
        __syncthreads();

        const float4* s4 = (const float4*)sh;
        float4 ca = s4[lane];                       // prefetch step 0
        float4 cb = s4[64 + lane];

        for (int t = 0; t < STEPS; ++t) {
            int tn = (t + 1) & (STEPS - 1);
            float4 na = s4[tn * 128 + lane];        // prefetch next (wraps)
            float4 nb = s4[tn * 128 + 64 + lane];

            // candidate global indices: sbase + {2*lane, 2*lane+1,
            //                                    128+2*lane, 128+2*lane+1}
            const int sbase = pass * HALF + t * 256;

            float dx0 = q0 - ca.x, dy0 = q1 - ca.y;
            float dx1 = q0 - ca.z, dy1 = q1 - ca.w;
            float dx2 = q0 - cb.x, dy2 = q1 - cb.y;
            float dx3 = q0 - cb.z, dy3 = q1 - cb.w;
            float nd0 = dx0 * dx0 + dy0 * dy0;
            float nd1 = dx1 * dx1 + dy1 * dy1;
            float nd2 = dx2 * dx2 + dy2 * dy2;
            float nd3 = dx3 * dx3 + dy3 * dy3;

            unsigned long long m;
            m = __ballot(__float_as_uint(nd0) <= thr);
            while (m) INSERT_EVENT(nd0, 2 * l)
            m = __ballot(__float_as_uint(nd1) <= thr);
            while (m) INSERT_EVENT(nd1, 2 * l + 1)
            m = __ballot(__float_as_uint(nd2) <= thr);
            while (m) INSERT_EVENT(nd2, 128 + 2 * l)
            m = __ballot(__float_as_uint(nd3) <= thr);
            while (m) INSERT_EVENT(nd3, 128 + 2 * l + 1)

            ca = na;
            cb = nb;
        }
    }
#undef INSERT_EVENT

    if (lane < K_NN)
        midx[qg * K_NN + lane] = (int)(key & 0x1FFFu);
}

// ---------------------------------------------------------------------------
// k3: scrambled gather + log-sum-exp. One thread per (n,k) pair (131072).
// A[k,n] = midx[(k*(N/K) + n/K)*K + (n%K)]; distance recomputed exactly with
// the polynomial applied on the fly. 1024-thread blocks -> 128 atomics total.
// ---------------------------------------------------------------------------
__global__ __launch_bounds__(1024) void k3_final(const float* __restrict__ ch1,
                                                 const float* __restrict__ ch2,
                                                 const float* __restrict__ M1,
                                                 const float* __restrict__ M2,
                                                 const int* __restrict__ midx,
                                                 float* __restrict__ out, int N) {
    const float a0 = M1[0], a1 = M1[1], a2 = M1[2], a3 = M1[3];
    const float b0 = M2[0], b1 = M2[1], b2 = M2[2], b3 = M2[3];

    int t = blockIdx.x * 1024 + threadIdx.x;  // [0, N*K)
    int n = t >> 4;
    int k = t & 15;
    int g = n >> 4;          // n / K
    int r = n & 15;          // n % K

    int j = k * (N / K_NN) + g;
    int a = midx[j * K_NN + r];
    float2 cp = ((const float2*)ch2)[a];
    float cx = a0 + a1 * cp.y + cp.x * (a2 + a3 * cp.y);
    float cy = b0 + b1 * cp.y + cp.x * (b2 + b3 * cp.y);
    float dx = ch1[2 * n + 0] - cx;
    float dy = ch1[2 * n + 1] - cy;
    float term = expf(-(dx * dx + dy * dy) * (1.0f / 4.5f));

    // sum over k within each 16-lane group
#pragma unroll
    for (int off = 8; off; off >>= 1) term += __shfl_down(term, off, 16);

    float v = 0.0f;
    if (k == 0) {
        float expD = term / (float)N;
        v = (expD != 0.0f) ? logf(expD) : 0.0f;
    }
#pragma unroll
    for (int off = 32; off; off >>= 1) v += __shfl_down(v, off, 64);

    __shared__ float red[16];
    int lane = threadIdx.x & 63;
    int wv = threadIdx.x >> 6;
    if (lane == 0) red[wv] = v;
    __syncthreads();
    if (threadIdx.x == 0) {
        float s = 0.0f;
#pragma unroll
        for (int i = 0; i < 16; ++i) s += red[i];
        atomicAdd(out, -s);
    }
}

// ---------------------------------------------------------------------------
extern "C" void kernel_launch(void* const* d_in, const int* in_sizes, int n_in,
                              void* d_out, int out_size, void* d_ws, size_t ws_size,
                              hipStream_t stream) {
    const float* ch1 = (const float*)d_in[0];
    const float* ch2 = (const float*)d_in[1];
    const float* M1  = (const float*)d_in[2];
    const float* M2  = (const float*)d_in[3];
    float* out = (float*)d_out;
    const int N = in_sizes[0] / 2;   // 8192

    int* midx = (int*)d_ws;          // 512 KB

    k1_knn<<<N / WPB, 1024, 0, stream>>>(ch1, ch2, M1, M2, midx, out);

    k3_final<<<(N * K_NN) / 1024, 1024, 0, stream>>>(ch1, ch2, M1, M2, midx, out, N);
}